// Round 6
// baseline (247.608 us; speedup 1.0000x reference)
//
#include <hip/hip_runtime.h>

// LinearSpline forward, C=64 channels, SIZE=51 knots, RANGE=1 -> GRID=0.04 (odd SIZE, no EVEN shift)
#define C_NUM  64
#define S_SIZE 51

// f32 boundary notes:
//   -(GRID*25) -> f32 = -1.0f ; -1.0f/0.04f = exactly -25.0f
//   GRID*24    -> f32 = 0.96f ; 0.96f/0.04f = exactly 24.0f
// We clamp the QUOTIENT at [-25.0f, 24.0f], so the extrapolation cell is exact even though
// d = xs*25.0f differs from xs/0.04f by <=1 ulp (interior floor flips land on knots where the
// piecewise-linear spline is continuous -> error ~ulp * slope, negligible vs 0.1 threshold).
#define GRID_F     0.04f
#define INV_GRID_F 25.0f
#define Q_LO      -25.0f
#define Q_HI       24.0f

// clang native 4-float vector (HIP's float4 is a struct; nontemporal builtin needs a real vector)
typedef float nfloat4 __attribute__((ext_vector_type(4)));

// ---------- prologue: Lipschitz projection -> ws = cv[64*51] | s[64] | inv[64] ----------
__global__ __launch_bounds__(256) void spline_project(
    const float* __restrict__ coef,
    const float* __restrict__ scale,
    float* __restrict__ ws)
{
    __shared__ float s_cs[C_NUM * S_SIZE];
    __shared__ float s_cv[C_NUM * S_SIZE];

    for (int i = threadIdx.x; i < C_NUM * S_SIZE; i += 256) s_cs[i] = coef[i];
    __syncthreads();

    if (threadIdx.x < C_NUM) {
        const float* p = &s_cs[threadIdx.x * S_SIZE];
        float*       q = &s_cv[threadIdx.x * S_SIZE];
        float acc = 0.0f;
        q[0] = 0.0f;
        for (int j = 0; j < S_SIZE - 1; ++j) {
            float sl = p[j + 1] - p[j];
            sl = fminf(fmaxf(sl, 0.0f), GRID_F);
            acc += sl;
            q[j + 1] = acc;
        }
        float ctr = q[S_SIZE / 2];
        for (int j = 0; j < S_SIZE; ++j) q[j] -= ctr;

        float s = scale[threadIdx.x];
        ws[C_NUM * S_SIZE + threadIdx.x]          = s;
        ws[C_NUM * S_SIZE + C_NUM + threadIdx.x]  = 1.0f / s;
    }
    __syncthreads();

    for (int i = threadIdx.x; i < C_NUM * S_SIZE; i += 256) ws[i] = s_cv[i];
}

// ---------- main elementwise kernel ----------
__device__ __forceinline__ nfloat4 spline4(nfloat4 v, float s, float inv, const float* __restrict__ cvc)
{
    nfloat4 r;
#pragma unroll
    for (int k = 0; k < 4; ++k) {
        float xs = v[k] * s;
        float d  = xs * INV_GRID_F;                 // replaces f32 division (see header note)
        float dc = fminf(fmaxf(d, Q_LO), Q_HI);
        float fl = floorf(dc);
        float fr = d - fl;                          // unclamped quotient minus floored (ref semantics)
        int   il = 25 + (int)fl;                    // in [0, 49]
        float a  = cvc[il];
        float b  = cvc[il + 1];
        r[k] = (b * fr + a * (1.0f - fr)) * inv;    // exact ref expression order
    }
    return r;
}

__global__ __launch_bounds__(256, 8) void linearspline_fwd(
    const float* __restrict__ x,
    const float* __restrict__ ws,      // cv[3264] | s[64] | inv[64]
    float* __restrict__ out,
    int nvec)
{
    __shared__ float s_cv[C_NUM * S_SIZE];
    __shared__ float s_s[C_NUM];
    __shared__ float s_inv[C_NUM];

    for (int i = threadIdx.x; i < C_NUM * S_SIZE; i += 256) s_cv[i] = ws[i];
    if (threadIdx.x < C_NUM) {
        s_s[threadIdx.x]   = ws[C_NUM * S_SIZE + threadIdx.x];
        s_inv[threadIdx.x] = ws[C_NUM * S_SIZE + C_NUM + threadIdx.x];
    }
    __syncthreads();

    const nfloat4* xv = (const nfloat4*)x;
    nfloat4*       ov = (nfloat4*)out;
    const int stride = gridDim.x * blockDim.x;
    int i = blockIdx.x * blockDim.x + threadIdx.x;

    // Launch config guarantees stride % (4096*64) == 0 (4096 float4 per channel-row, 64 channels),
    // so the channel is loop-invariant per thread: hoist c/s/inv/cvc.
    const int   c   = (i >> 12) & (C_NUM - 1);
    const float s   = s_s[c];
    const float inv = s_inv[c];
    const float* cvc = &s_cv[c * S_SIZE];

    // unroll x2: two independent float4 streams per iteration for ILP
    for (; i + stride < nvec; i += 2 * stride) {
        nfloat4 v0 = xv[i];
        nfloat4 v1 = xv[i + stride];
        nfloat4 r0 = spline4(v0, s, inv, cvc);
        nfloat4 r1 = spline4(v1, s, inv, cvc);
        __builtin_nontemporal_store(r0, &ov[i]);
        __builtin_nontemporal_store(r1, &ov[i + stride]);
    }
    for (; i < nvec; i += stride) {
        nfloat4 v = xv[i];
        nfloat4 r = spline4(v, s, inv, cvc);
        __builtin_nontemporal_store(r, &ov[i]);
    }
}

extern "C" void kernel_launch(void* const* d_in, const int* in_sizes, int n_in,
                              void* d_out, int out_size, void* d_ws, size_t ws_size,
                              hipStream_t stream) {
    const float* x     = (const float*)d_in[0];
    const float* coef  = (const float*)d_in[1];
    const float* scale = (const float*)d_in[2];
    float*       out   = (float*)d_out;
    float*       ws    = (float*)d_ws;

    const int n    = in_sizes[0];      // 33,554,432 (divisible by 4)
    const int nvec = n >> 2;           // 8,388,608

    spline_project<<<1, 256, 0, stream>>>(coef, scale, ws);

    // 2048 blocks x 256 threads = 524288 threads; stride 524288 = 2 * (4096*64) -> channel invariant
    linearspline_fwd<<<2048, 256, 0, stream>>>(x, ws, out, nvec);
}